// Round 5
// baseline (510.301 us; speedup 1.0000x reference)
//
#include <hip/hip_runtime.h>

typedef _Float16 f16;
typedef _Float16 f16x2 __attribute__((ext_vector_type(2)));
typedef _Float16 f16x4 __attribute__((ext_vector_type(4)));
typedef _Float16 f16x8 __attribute__((ext_vector_type(8)));
typedef float floatx4 __attribute__((ext_vector_type(4)));

// Problem constants (fixed by the reference)
constexpr int NC = 100000;   // cards
constexpr int NM = 20000;    // merchants
constexpr int NE = 400000;   // edges per edge-type

// d_out layout (floats), concat of (xc2, xm2, pred_c, pred_m, risk_c, risk_m)
constexpr int OFF_XM2 = NC * 128;
constexpr int OFF_PC  = OFF_XM2 + NM * 128;
constexpr int OFF_PM  = OFF_PC + NC * 2;
constexpr int OFF_RC  = OFF_PM + NM * 2;
constexpr int OFF_RM  = OFF_RC + NC;

__device__ __forceinline__ int bpermi(int v, int srclane) {
  return __builtin_amdgcn_ds_bpermute(srclane << 2, v);
}
__device__ __forceinline__ float bpermf(float v, int srclane) {
  int r = __builtin_amdgcn_ds_bpermute(srclane << 2, __builtin_bit_cast(int, v));
  return __builtin_bit_cast(float, r);
}

// ---------------------------------------------------------------- fused prep
// blocks 0..255: zero counters+stats. block 256: a_d GEMV vectors + bias concat.
// blocks 257..276: swizzle W matrices into MFMA B-fragment fp16 order.
__global__ void __launch_bounds__(256) k_prep(
    int* zero_base, int nzero, int* stats_i,
    const float* W0, const float* a0, float* v0,
    const float* W1, const float* a1, float* v1,
    const float* W2, const float* a2, float* v2,
    const float* W3, const float* a3, float* v3,
    const float* cb1, const float* mb1, const float* rb1, float* bC, float* bM,
    const float* S0, const float* S1, const float* S2, const float* S3,
    const float* c1, const float* m1, const float* r1,
    f16* BfL0cm, f16* BfL0mc, f16* BfL1cm, f16* BfL1mc, f16* BfC, f16* BfM) {
  int b = blockIdx.x, t = threadIdx.x;
  if (b < 256) {
    for (int i = b * 256 + t; i < nzero + 4; i += 256 * 256) {
      if (i < nzero) zero_base[i] = 0; else stats_i[i - nzero] = 0;
    }
  } else if (b == 256) {
    const float* Wd[4] = {W0, W1, W2, W3};
    const float* ad[4] = {a0, a1, a2, a3};
    float* vd[4] = {v0, v1, v2, v3};
    for (int idx = t; idx < 1536; idx += 256) {
      int mat, base;
      if (idx < 256)       { mat = 0; base = 0; }
      else if (idx < 512)  { mat = 1; base = 256; }
      else if (idx < 1024) { mat = 2; base = 512; }
      else                 { mat = 3; base = 1024; }
      int local = idx - base, k = local >> 2, h = local & 3;
      const float* W = Wd[mat]; const float* a = ad[mat];
      float s = 0.f;
      for (int c = 0; c < 32; ++c) s += W[k * 128 + h * 32 + c] * a[h * 32 + c];
      vd[mat][local] = s;
    }
    if (t < 128) {
      bC[t] = (t < 64) ? cb1[t] : rb1[t - 64];
      bM[t] = (t < 64) ? mb1[t] : rb1[t - 64];
    }
  } else {
    int s = b - 257;
    const float* Wp = nullptr; const float* cA = nullptr; const float* cB = nullptr;
    f16* dst; int kt;
    if (s < 2)       { Wp = S0; dst = BfL0cm; kt = s; }
    else if (s < 4)  { Wp = S1; dst = BfL0mc; kt = s - 2; }
    else if (s < 8)  { Wp = S2; dst = BfL1cm; kt = s - 4; }
    else if (s < 12) { Wp = S3; dst = BfL1mc; kt = s - 8; }
    else if (s < 16) { cA = c1; cB = r1; dst = BfC; kt = s - 12; }
    else             { cA = m1; cB = r1; dst = BfM; kt = s - 16; }
    for (int e = t; e < 512; e += 256) {
      int lane = e & 63, ct = e >> 6;
      int m = lane & 15, q = lane >> 4;
      int col = ct * 16 + m;
      f16x8 frag;
      #pragma unroll
      for (int j = 0; j < 8; ++j) {
        int k = kt * 32 + q * 8 + j;
        float val = Wp ? Wp[k * 128 + col]
                       : (col < 64 ? cA[k * 64 + col] : cB[k * 64 + (col - 64)]);
        frag[j] = (f16)val;
      }
      *reinterpret_cast<f16x8*>(&dst[(size_t)((kt * 8 + ct) * 64 + lane) * 8]) = frag;
    }
  }
}

// ---------------------------------------------------------------- CSR build
__global__ void k_hist(const int* cm_dst, const int* mc_dst, int* cnt_cm, int* cnt_mc) {
  int i = blockIdx.x * blockDim.x + threadIdx.x;
  int stride = gridDim.x * blockDim.x;
  for (; i < NE; i += stride) {
    atomicAdd(&cnt_cm[cm_dst[i]], 1);
    atomicAdd(&cnt_mc[mc_dst[i]], 1);
  }
}

__global__ void __launch_bounds__(256) k_scan1(const int* cnt_cm, const int* cnt_mc,
                                               int* offs_cm, int* offs_mc, int* parts) {
  int b = blockIdx.x;
  const int* cnt; int* offs; int n, chunk;
  if (b < 20) { cnt = cnt_cm; offs = offs_cm; n = NM; chunk = b; }
  else        { cnt = cnt_mc; offs = offs_mc; n = NC; chunk = b - 20; }
  int t = threadIdx.x;
  int base = chunk * 1024;
  int v[4]; int tsum = 0;
  #pragma unroll
  for (int j = 0; j < 4; ++j) {
    int idx = base + t * 4 + j;
    v[j] = (idx < n) ? cnt[idx] : 0;
    tsum += v[j];
  }
  __shared__ int sd[256];
  sd[t] = tsum; __syncthreads();
  for (int off = 1; off < 256; off <<= 1) {
    int x = (t >= off) ? sd[t - off] : 0;
    __syncthreads();
    sd[t] += x;
    __syncthreads();
  }
  int excl = sd[t] - tsum;
  int r = excl;
  #pragma unroll
  for (int j = 0; j < 4; ++j) {
    int idx = base + t * 4 + j;
    if (idx < n) offs[idx] = r;
    r += v[j];
  }
  if (t == 0) parts[b] = sd[255];
}

__global__ void __launch_bounds__(256) k_scan2(int* parts) {
  int b = blockIdx.x;
  int base = (b == 0) ? 0 : 20;
  int n = (b == 0) ? 20 : 98;
  int t = threadIdx.x;
  __shared__ int sd[128];
  int v = 0;
  if (t < 128) { v = (t < n) ? parts[base + t] : 0; sd[t] = v; }
  __syncthreads();
  for (int off = 1; off < 128; off <<= 1) {
    int x = 0;
    if (t < 128 && t >= off) x = sd[t - off];
    __syncthreads();
    if (t < 128) sd[t] += x;
    __syncthreads();
  }
  if (t < 128 && t < n) parts[base + t] = sd[t] - v;
}

__global__ void k_scan3(int* offs_cm, int* offs_mc, int* cur_cm, int* cur_mc, const int* parts) {
  int i = blockIdx.x * blockDim.x + threadIdx.x;
  if (i < NM) {
    int val = offs_cm[i] + parts[i >> 10];
    offs_cm[i] = val; cur_cm[i] = val;
  } else if (i < NM + NC) {
    int j = i - NM;
    int val = offs_mc[j] + parts[20 + (j >> 10)];
    offs_mc[j] = val; cur_mc[j] = val;
  }
  if (i == 0) { offs_cm[NM] = NE; offs_mc[NC] = NE; }
}

__global__ void k_scatter(const int* cm_src, const int* cm_dst,
                          const int* mc_src, const int* mc_dst,
                          int* cur_cm, int* cur_mc, int* csr_cm, int* csr_mc) {
  int i = blockIdx.x * blockDim.x + threadIdx.x;
  int stride = gridDim.x * blockDim.x;
  for (; i < NE; i += stride) {
    int p = atomicAdd(&cur_cm[cm_dst[i]], 1);
    csr_cm[p] = cm_src[i];
    int q = atomicAdd(&cur_mc[mc_dst[i]], 1);
    csr_mc[q] = mc_src[i];
  }
}

// ---------------------------------------------------------------- MFMA GEMM
// 64-row x 128-col tile per 256-thread block; 4 waves, each: 16 rows x 128 cols
// via 8 col-tiles of mfma_f32_16x16x32_f16 over K/32 k-tiles.
// C/D layout: col = ct*16 + (lane&15), row = (lane>>4)*4 + reg
struct GemmSide {
  const void* x; const f16* Bf;
  const float* asrc; const float* v; f16* hs; float* asO; float* adO;   // EPI 0
  const float* bias; const float* wnum; const float* den; float* outx;  // EPI 1
  const float* W2; const float* B2; const float* w2r; const float* b2r;
  float* pred; float* risk;
  int M;
};

template<int K, int EPI, bool IN16>
__global__ void __launch_bounds__(256) k_gemm(GemmSide A, GemmSide B, int gridA) {
  constexpr int PP = K + 8;        // fp16 pitch (row stride bytes = 2*PP, 16B aligned)
  __shared__ f16 xs16[64 * PP];
  const bool isA = (int)blockIdx.x < gridA;
  GemmSide S = isA ? A : B;
  const int blk = isA ? (int)blockIdx.x : (int)blockIdx.x - gridA;
  const int rows0 = blk * 64;
  const int t = (int)threadIdx.x;
  float invden_s = 0.f;
  if constexpr (EPI == 1) invden_s = 1.0f / S.den[0];
  if constexpr (!IN16) {
    constexpr int F4 = K / 4;
    const float4* x4 = reinterpret_cast<const float4*>(S.x);
    #pragma unroll
    for (int ii = 0; ii < (64 * F4) / 256; ++ii) {
      int idx = t + ii * 256;
      int r = idx / F4, f = idx % F4;
      int gr = rows0 + r;
      float4 val = {0.f, 0.f, 0.f, 0.f};
      if (gr < S.M) val = x4[(size_t)gr * F4 + f];
      f16x4 hv; hv.x = (f16)val.x; hv.y = (f16)val.y; hv.z = (f16)val.z; hv.w = (f16)val.w;
      *reinterpret_cast<f16x4*>(&xs16[r * PP + f * 4]) = hv;
      if constexpr (EPI == 1) {
        if (gr < S.M) {
          float w = S.wnum[gr] * invden_s;
          float4 ov = {val.x * w, val.y * w, val.z * w, val.w * w};
          *reinterpret_cast<float4*>(&S.outx[(size_t)gr * 128 + f * 4]) = ov;
        }
      }
    }
  } else {
    constexpr int F8 = K / 8;
    const f16x8* x8 = reinterpret_cast<const f16x8*>(S.x);
    #pragma unroll
    for (int ii = 0; ii < (64 * F8) / 256; ++ii) {
      int idx = t + ii * 256;
      int r = idx / F8, f = idx % F8;
      int gr = rows0 + r;
      f16x8 val = {0, 0, 0, 0, 0, 0, 0, 0};
      if (gr < S.M) val = x8[(size_t)gr * F8 + f];
      *reinterpret_cast<f16x8*>(&xs16[r * PP + f * 8]) = val;
      if constexpr (EPI == 1) {
        if (gr < S.M) {
          float w = S.wnum[gr] * invden_s;
          float4 o1 = {(float)val[0] * w, (float)val[1] * w, (float)val[2] * w, (float)val[3] * w};
          float4 o2 = {(float)val[4] * w, (float)val[5] * w, (float)val[6] * w, (float)val[7] * w};
          *reinterpret_cast<float4*>(&S.outx[(size_t)gr * 128 + f * 8]) = o1;
          *reinterpret_cast<float4*>(&S.outx[(size_t)gr * 128 + f * 8 + 4]) = o2;
        }
      }
    }
  }
  __syncthreads();
  const int lane = t & 63, w = t >> 6;
  const int m = lane & 15, q = lane >> 4;
  const int rbase = w * 16;
  floatx4 acc[8];
  #pragma unroll
  for (int ct = 0; ct < 8; ++ct) acc[ct] = {0.f, 0.f, 0.f, 0.f};
  const f16x8* Bf8 = reinterpret_cast<const f16x8*>(S.Bf);
  #pragma unroll
  for (int kt = 0; kt < K / 32; ++kt) {
    f16x8 a = *reinterpret_cast<const f16x8*>(&xs16[(rbase + m) * PP + kt * 32 + q * 8]);
    #pragma unroll
    for (int ct = 0; ct < 8; ++ct) {
      f16x8 b = Bf8[(kt * 8 + ct) * 64 + lane];
      acc[ct] = __builtin_amdgcn_mfma_f32_16x16x32_f16(a, b, acc[ct], 0, 0, 0);
    }
  }
  if constexpr (EPI == 0) {
    // ---- hs f16 store: pair columns via xor-1 shuffle
    #pragma unroll
    for (int reg = 0; reg < 4; ++reg) {
      int gr = rows0 + rbase + q * 4 + reg;
      bool ok = gr < S.M;
      #pragma unroll
      for (int cp = 0; cp < 4; ++cp) {
        float v0 = acc[2 * cp][reg], v1 = acc[2 * cp + 1][reg];
        float w0 = __shfl_xor(v0, 1), w1 = __shfl_xor(v1, 1);
        bool even = (m & 1) == 0;
        f16x2 pr;
        pr.x = (f16)(even ? v0 : w1);
        pr.y = (f16)(even ? w0 : v1);
        int col = even ? (2 * cp) * 16 + m : (2 * cp + 1) * 16 + m - 1;
        if (ok) *reinterpret_cast<f16x2*>(&S.hs[(size_t)gr * 128 + col]) = pr;
      }
    }
    // ---- a_s
    float as0[4], as1[4];
    #pragma unroll
    for (int h = 0; h < 4; ++h) { as0[h] = S.asrc[h * 32 + m]; as1[h] = S.asrc[h * 32 + 16 + m]; }
    #pragma unroll
    for (int reg = 0; reg < 4; ++reg) {
      float p[4];
      #pragma unroll
      for (int h = 0; h < 4; ++h)
        p[h] = acc[2 * h][reg] * as0[h] + acc[2 * h + 1][reg] * as1[h];
      #pragma unroll
      for (int off = 1; off < 16; off <<= 1) {
        #pragma unroll
        for (int h = 0; h < 4; ++h) p[h] += __shfl_xor(p[h], off);
      }
      int gr = rows0 + rbase + q * 4 + reg;
      if (m == 0 && gr < S.M) {
        float4 pv = {p[0], p[1], p[2], p[3]};
        *reinterpret_cast<float4*>(&S.asO[gr * 4]) = pv;
      }
    }
    // ---- a_d: GEMV x @ v from LDS
    float qd[4] = {0.f, 0.f, 0.f, 0.f};
    const float4* v4p = reinterpret_cast<const float4*>(S.v);
    constexpr int KS = K / 4;
    #pragma unroll
    for (int i = 0; i < KS; ++i) {
      int k = q * KS + i;
      float xv = (float)xs16[(rbase + m) * PP + k];
      float4 vk = v4p[k];
      qd[0] += xv * vk.x; qd[1] += xv * vk.y; qd[2] += xv * vk.z; qd[3] += xv * vk.w;
    }
    #pragma unroll
    for (int h = 0; h < 4; ++h) {
      qd[h] += __shfl_xor(qd[h], 16);
      qd[h] += __shfl_xor(qd[h], 32);
    }
    int gr2 = rows0 + rbase + m;
    if (q == 0 && gr2 < S.M) {
      float4 qv = {qd[0], qd[1], qd[2], qd[3]};
      *reinterpret_cast<float4*>(&S.adO[gr2 * 4]) = qv;
    }
  } else {
    // ---- fused MLP-2 + heads
    float wn[4];
    #pragma unroll
    for (int reg = 0; reg < 4; ++reg) {
      int gr = rows0 + rbase + q * 4 + reg;
      wn[reg] = (gr < S.M) ? S.wnum[gr] * invden_s : 0.f;
    }
    float bct[8], w2c0[4], w2c1[4], w2rv[4];
    #pragma unroll
    for (int ct = 0; ct < 8; ++ct) bct[ct] = S.bias[ct * 16 + m];
    #pragma unroll
    for (int ct = 0; ct < 4; ++ct) {
      int col = ct * 16 + m;
      w2c0[ct] = S.W2[col * 2];
      w2c1[ct] = S.W2[col * 2 + 1];
      w2rv[ct] = S.w2r[col];
    }
    #pragma unroll
    for (int reg = 0; reg < 4; ++reg) {
      float p0 = 0.f, p1 = 0.f, rr = 0.f;
      #pragma unroll
      for (int ct = 0; ct < 4; ++ct) {
        float hv = fmaxf(acc[ct][reg] * wn[reg] + bct[ct], 0.f);
        p0 += hv * w2c0[ct];
        p1 += hv * w2c1[ct];
      }
      #pragma unroll
      for (int ct = 4; ct < 8; ++ct) {
        float hv = fmaxf(acc[ct][reg] * wn[reg] + bct[ct], 0.f);
        rr += hv * w2rv[ct - 4];
      }
      #pragma unroll
      for (int off = 1; off < 16; off <<= 1) {
        p0 += __shfl_xor(p0, off);
        p1 += __shfl_xor(p1, off);
        rr += __shfl_xor(rr, off);
      }
      int gr = rows0 + rbase + q * 4 + reg;
      if (m == 0 && gr < S.M) {
        float2 pp = {p0 + S.B2[0], p1 + S.B2[1]};
        *reinterpret_cast<float2*>(&S.pred[gr * 2]) = pp;
        float z = rr + S.b2r[0];
        S.risk[gr] = 1.f / (1.f + __expf(-z));
      }
    }
  }
}

// ---------------------------------------------------------------- aggregation
// ONE WAVE per dst, 4 dst per block. Paired-edge gather: lanes 0-31 = edge j
// (f16x4 = 4 channels/lane), lanes 32-63 = edge j+1. Online softmax per
// 16-edge chunk (weight role: lane = edge*4 + head). fp16 output.
struct AggSide {
  const int* offs; const int* csr; const float* as_; const float* ad;
  const f16* hs; const float* bias; f16* out;
  const float* attw; const float* attb; float* logv;
};

__global__ void __launch_bounds__(256) k_agg(AggSide A, AggSide B, int ndstA, int ntot) {
  const int wid = (int)blockIdx.x * 4 + ((int)threadIdx.x >> 6);
  if (wid >= ntot) return;
  const bool isA = wid < ndstA;
  const AggSide S = isA ? A : B;
  const int d = isA ? wid : wid - ndstA;
  const int lane = (int)threadIdx.x & 63;
  const int we = lane >> 2, wh = lane & 3;   // weight role: edge-in-chunk, head
  const int h2 = lane >> 5, cl = lane & 31;  // gather role: half (edge parity), channel group
  const int gh = cl >> 3;                    // head of this channel group (4 ch)
  const int beg = S.offs[d], end = S.offs[d + 1];
  const float adv = S.ad[d * 4 + wh];
  const f16* __restrict__ hsp = S.hs;
  float m_run = -1e30f, den = 0.f;
  floatx4 acc = {0.f, 0.f, 0.f, 0.f};
  for (int base = beg; base < end; base += 16) {
    const int n = min(16, end - base);
    int s = 0; float e = -1e30f;
    if (we < n) {
      s = S.csr[base + we];
      float ev = S.as_[s * 4 + wh] + adv;
      e = (ev > 0.f) ? ev : 0.2f * ev;
    }
    float cm = e;
    #pragma unroll
    for (int msk = 4; msk < 64; msk <<= 1) cm = fmaxf(cm, __shfl_xor(cm, msk));
    const float m_new = fmaxf(m_run, cm);
    const float scale = __expf(m_run - m_new);   // 0 on first chunk
    const float w = __expf(e - m_new);           // 0 for invalid lanes
    float ws = w;
    #pragma unroll
    for (int msk = 4; msk < 64; msk <<= 1) ws += __shfl_xor(ws, msk);
    den = den * scale + ws;
    m_run = m_new;
    const float sg = bpermf(scale, gh);
    acc.x *= sg; acc.y *= sg; acc.z *= sg; acc.w *= sg;
    int jb = 0;
    for (; jb + 4 <= n; jb += 4) {
      int sa = bpermi(s, (jb + h2) * 4);
      int sb = bpermi(s, (jb + h2 + 2) * 4);
      float wa = bpermf(w, (jb + h2) * 4 + gh);
      float wb = bpermf(w, (jb + h2 + 2) * 4 + gh);
      f16x4 ha = *reinterpret_cast<const f16x4*>(&hsp[sa * 128 + cl * 4]);
      f16x4 hb = *reinterpret_cast<const f16x4*>(&hsp[sb * 128 + cl * 4]);
      acc.x += wa * (float)ha.x + wb * (float)hb.x;
      acc.y += wa * (float)ha.y + wb * (float)hb.y;
      acc.z += wa * (float)ha.z + wb * (float)hb.z;
      acc.w += wa * (float)ha.w + wb * (float)hb.w;
    }
    for (int j = jb + h2; j < n; j += 2) {
      int sj = bpermi(s, j * 4);
      float wj = bpermf(w, j * 4 + gh);
      f16x4 hj = *reinterpret_cast<const f16x4*>(&hsp[sj * 128 + cl * 4]);
      acc.x += wj * (float)hj.x;
      acc.y += wj * (float)hj.y;
      acc.z += wj * (float)hj.z;
      acc.w += wj * (float)hj.w;
    }
  }
  // combine halves (both halves end with the full sum)
  acc.x += __shfl_xor(acc.x, 32);
  acc.y += __shfl_xor(acc.y, 32);
  acc.z += __shfl_xor(acc.z, 32);
  acc.w += __shfl_xor(acc.w, 32);
  const float deng = bpermf(den, gh);
  const float invden = (deng > 0.f) ? 1.f / deng : 0.f;
  const float4 b4 = *reinterpret_cast<const float4*>(&S.bias[cl * 4]);
  float o0 = acc.x * invden + b4.x;
  float o1 = acc.y * invden + b4.y;
  float o2 = acc.z * invden + b4.z;
  float o3 = acc.w * invden + b4.w;
  if (S.attw) {
    const float4 aw = *reinterpret_cast<const float4*>(&S.attw[cl * 4]);
    float sl = o0 * aw.x + o1 * aw.y + o2 * aw.z + o3 * aw.w;
    #pragma unroll
    for (int msk = 1; msk < 32; msk <<= 1) sl += __shfl_xor(sl, msk);
    if (lane == 0) S.logv[d] = sl + S.attb[0];
  }
  if (h2 == 0) {
    f16x4 ov;
    ov.x = (f16)o0; ov.y = (f16)o1; ov.z = (f16)o2; ov.w = (f16)o3;
    *reinterpret_cast<f16x4*>(&S.out[d * 128 + cl * 4]) = ov;
  }
}

// ---------------------------------------------------------------- global softmax
__global__ void __launch_bounds__(1024) k_stats(const float* logc, const float* logm, float* stats) {
  const float* src = (blockIdx.x == 0) ? logc : logm;
  int n = (blockIdx.x == 0) ? NC : NM;
  float m = -1e30f;
  for (int i = threadIdx.x; i < n; i += 1024) m = fmaxf(m, src[i]);
  __shared__ float sd[1024];
  sd[threadIdx.x] = m; __syncthreads();
  for (int off = 512; off > 0; off >>= 1) {
    if ((int)threadIdx.x < off) sd[threadIdx.x] = fmaxf(sd[threadIdx.x], sd[threadIdx.x + off]);
    __syncthreads();
  }
  if (threadIdx.x == 0) stats[blockIdx.x] = sd[0];
}

__global__ void __launch_bounds__(256) k_expsum(float* logc, float* logm, float* stats) {
  bool card = (int)blockIdx.x < 256;
  float* logv = card ? logc : logm;
  int n = card ? NC : NM;
  float mx = card ? stats[0] : stats[1];
  int b0 = card ? (int)blockIdx.x : (int)blockIdx.x - 256;
  int nb = card ? 256 : 64;
  float local = 0.f;
  for (int i = b0 * 256 + (int)threadIdx.x; i < n; i += nb * 256) {
    float e = __expf(logv[i] - mx);
    logv[i] = e;        // store numerator for later
    local += e;
  }
  __shared__ float sd[256];
  sd[threadIdx.x] = local; __syncthreads();
  for (int off = 128; off > 0; off >>= 1) {
    if ((int)threadIdx.x < off) sd[threadIdx.x] += sd[threadIdx.x + off];
    __syncthreads();
  }
  if (threadIdx.x == 0) atomicAdd(card ? &stats[2] : &stats[3], sd[0]);
}

// ---------------------------------------------------------------- launch
extern "C" void kernel_launch(void* const* d_in, const int* in_sizes, int n_in,
                              void* d_out, int out_size, void* d_ws, size_t ws_size,
                              hipStream_t stream) {
  (void)in_sizes; (void)n_in; (void)out_size; (void)ws_size;
  const float* x_card    = (const float*)d_in[0];
  const float* x_mer     = (const float*)d_in[1];
  const float* l0cm_Wsrc = (const float*)d_in[2];
  const float* l0cm_Wdst = (const float*)d_in[3];
  const float* l0cm_asrc = (const float*)d_in[4];
  const float* l0cm_adst = (const float*)d_in[5];
  const float* l0cm_b    = (const float*)d_in[6];
  const float* l0mc_Wsrc = (const float*)d_in[7];
  const float* l0mc_Wdst = (const float*)d_in[8];
  const float* l0mc_asrc = (const float*)d_in[9];
  const float* l0mc_adst = (const float*)d_in[10];
  const float* l0mc_b    = (const float*)d_in[11];
  const float* l1cm_Wsrc = (const float*)d_in[12];
  const float* l1cm_Wdst = (const float*)d_in[13];
  const float* l1cm_asrc = (const float*)d_in[14];
  const float* l1cm_adst = (const float*)d_in[15];
  const float* l1cm_b    = (const float*)d_in[16];
  const float* l1mc_Wsrc = (const float*)d_in[17];
  const float* l1mc_Wdst = (const float*)d_in[18];
  const float* l1mc_asrc = (const float*)d_in[19];
  const float* l1mc_adst = (const float*)d_in[20];
  const float* l1mc_b    = (const float*)d_in[21];
  const float* attw_c    = (const float*)d_in[22];
  const float* attb_c    = (const float*)d_in[23];
  const float* attw_m    = (const float*)d_in[24];
  const float* attb_m    = (const float*)d_in[25];
  const float* clsc_W1   = (const float*)d_in[26];
  const float* clsc_b1   = (const float*)d_in[27];
  const float* clsc_W2   = (const float*)d_in[28];
  const float* clsc_b2   = (const float*)d_in[29];
  const float* clsm_W1   = (const float*)d_in[30];
  const float* clsm_b1   = (const float*)d_in[31];
  const float* clsm_W2   = (const float*)d_in[32];
  const float* clsm_b2   = (const float*)d_in[33];
  const float* risk_W1   = (const float*)d_in[34];
  const float* risk_b1   = (const float*)d_in[35];
  const float* risk_W2   = (const float*)d_in[36];
  const float* risk_b2   = (const float*)d_in[37];
  const int*   cm_src    = (const int*)d_in[38];
  const int*   cm_dst    = (const int*)d_in[39];
  const int*   mc_src    = (const int*)d_in[40];
  const int*   mc_dst    = (const int*)d_in[41];
  float* out = (float*)d_out;

  float* base = (float*)d_ws;
  size_t o = 0;
  auto alloc = [&](size_t n) { float* p = base + o; o += (n + 3) & ~size_t(3); return p; };
  f16* hs_card = (f16*)alloc((size_t)NC * 64);   // f16 NC*128
  f16* xc1     = (f16*)alloc((size_t)NC * 64);   // f16 xc1 / xc2raw
  f16* hs_mer  = (f16*)alloc((size_t)NM * 64);
  f16* xm1     = (f16*)alloc((size_t)NM * 64);
  float* as_card = alloc((size_t)NC * 4);
  float* ad_card = alloc((size_t)NC * 4);
  float* as_mer  = alloc((size_t)NM * 4);
  float* ad_mer  = alloc((size_t)NM * 4);
  float* v_l0cm  = alloc(512);
  float* v_l0mc  = alloc(512);
  float* v_l1cm  = alloc(512);
  float* v_l1mc  = alloc(512);
  float* bC      = alloc(128);
  float* bM      = alloc(128);
  f16* Bf_l0cm = (f16*)alloc(64 * 128 / 2);
  f16* Bf_l0mc = (f16*)alloc(64 * 128 / 2);
  f16* Bf_l1cm = (f16*)alloc(128 * 128 / 2);
  f16* Bf_l1mc = (f16*)alloc(128 * 128 / 2);
  f16* Bf_catC = (f16*)alloc(128 * 128 / 2);
  f16* Bf_catM = (f16*)alloc(128 * 128 / 2);
  float* logc    = alloc(NC);
  float* logm    = alloc(NM);
  float* stats   = alloc(4);                  // [maxc, maxm, denc, denm]
  int* cnt_cm  = (int*)alloc(NM);
  int* cnt_mc  = (int*)alloc(NC);
  int* offs_cm = (int*)alloc(NM + 1);
  int* offs_mc = (int*)alloc(NC + 1);
  int* cur_cm  = (int*)alloc(NM);
  int* cur_mc  = (int*)alloc(NC);
  int* parts   = (int*)alloc(128);
  int* csr_cm  = (int*)alloc(NE);
  int* csr_mc  = (int*)alloc(NE);

  const dim3 B256(256);
  k_prep<<<dim3(277), B256, 0, stream>>>(
      cnt_cm, NM + NC, (int*)stats,
      l0cm_Wdst, l0cm_adst, v_l0cm, l0mc_Wdst, l0mc_adst, v_l0mc,
      l1cm_Wdst, l1cm_adst, v_l1cm, l1mc_Wdst, l1mc_adst, v_l1mc,
      clsc_b1, clsm_b1, risk_b1, bC, bM,
      l0cm_Wsrc, l0mc_Wsrc, l1cm_Wsrc, l1mc_Wsrc,
      clsc_W1, clsm_W1, risk_W1,
      Bf_l0cm, Bf_l0mc, Bf_l1cm, Bf_l1mc, Bf_catC, Bf_catM);
  k_hist<<<dim3(512), B256, 0, stream>>>(cm_dst, mc_dst, cnt_cm, cnt_mc);
  k_scan1<<<dim3(118), B256, 0, stream>>>(cnt_cm, cnt_mc, offs_cm, offs_mc, parts);
  k_scan2<<<dim3(2), B256, 0, stream>>>(parts);
  k_scan3<<<dim3(469), B256, 0, stream>>>(offs_cm, offs_mc, cur_cm, cur_mc, parts);
  k_scatter<<<dim3(512), B256, 0, stream>>>(cm_src, cm_dst, mc_src, mc_dst,
                                            cur_cm, cur_mc, csr_cm, csr_mc);
  const int gA = (NC + 63) / 64;   // 1563
  const int gB = (NM + 63) / 64;   // 313
  const int NTOT = NM + NC;        // 120000
  const int gAgg = (NTOT + 3) / 4; // 30000

  GemmSide sA, sB;
  AggSide aA, aB;
  // ---- layer 0 (fp32 inputs)
  sA = {x_card, Bf_l0cm, l0cm_asrc, v_l0mc, hs_card, as_card, ad_card,
        nullptr, nullptr, nullptr, nullptr, nullptr, nullptr, nullptr, nullptr,
        nullptr, nullptr, NC};
  sB = {x_mer, Bf_l0mc, l0mc_asrc, v_l0cm, hs_mer, as_mer, ad_mer,
        nullptr, nullptr, nullptr, nullptr, nullptr, nullptr, nullptr, nullptr,
        nullptr, nullptr, NM};
  k_gemm<64, 0, false><<<dim3(gA + gB), B256, 0, stream>>>(sA, sB, gA);
  aA = {offs_cm, csr_cm, as_card, ad_mer, hs_card, l0cm_b, xm1,
        nullptr, nullptr, nullptr};
  aB = {offs_mc, csr_mc, as_mer, ad_card, hs_mer, l0mc_b, xc1,
        nullptr, nullptr, nullptr};
  k_agg<<<dim3(gAgg), B256, 0, stream>>>(aA, aB, NM, NTOT);
  // ---- layer 1 (fp16 inputs)
  sA = {xc1, Bf_l1cm, l1cm_asrc, v_l1mc, hs_card, as_card, ad_card,
        nullptr, nullptr, nullptr, nullptr, nullptr, nullptr, nullptr, nullptr,
        nullptr, nullptr, NC};
  sB = {xm1, Bf_l1mc, l1mc_asrc, v_l1cm, hs_mer, as_mer, ad_mer,
        nullptr, nullptr, nullptr, nullptr, nullptr, nullptr, nullptr, nullptr,
        nullptr, nullptr, NM};
  k_gemm<128, 0, true><<<dim3(gA + gB), B256, 0, stream>>>(sA, sB, gA);
  aA = {offs_cm, csr_cm, as_card, ad_mer, hs_card, l1cm_b, xm1,
        attw_m, attb_m, logm};
  aB = {offs_mc, csr_mc, as_mer, ad_card, hs_mer, l1mc_b, xc1,
        attw_c, attb_c, logc};
  k_agg<<<dim3(gAgg), B256, 0, stream>>>(aA, aB, NM, NTOT);
  // ---- global node softmax stats
  k_stats<<<dim3(2), dim3(1024), 0, stream>>>(logc, logm, stats);
  k_expsum<<<dim3(320), B256, 0, stream>>>(logc, logm, stats);
  // ---- fused: xc2/xm2 outputs + MLP(hidden+heads) via MFMA (fp16 inputs)
  sA = {xc1, Bf_catC, nullptr, nullptr, nullptr, nullptr, nullptr,
        bC, logc, stats + 2, out,
        clsc_W2, clsc_b2, risk_W2, risk_b2,
        out + OFF_PC, out + OFF_RC, NC};
  sB = {xm1, Bf_catM, nullptr, nullptr, nullptr, nullptr, nullptr,
        bM, logm, stats + 3, out + OFF_XM2,
        clsm_W2, clsm_b2, risk_W2, risk_b2,
        out + OFF_PM, out + OFF_RM, NM};
  k_gemm<128, 1, true><<<dim3(gA + gB), B256, 0, stream>>>(sA, sB, gA);
}